// Round 1
// baseline (831.210 us; speedup 1.0000x reference)
//
#include <hip/hip_runtime.h>

// Self-attention B=4, S=4096, D=1024, fp32 in/out.
// Pipeline: cvt(x,W)->bf16 | GEMM_NT proj (Q,K natural; V transposed) |
// per-batch: scores=Q Kt /32 -> bf16 | in-place softmax | O = P Vt -> fp32.
// All GEMMs: NT bf16 MFMA 16x16x32, 128x128 tile, BK=64, 4 waves 2x2,
// LDS row stride 72 elems (144 B, 16B-aligned, conflict-benign).

typedef unsigned short u16;
typedef __attribute__((ext_vector_type(8))) short bf16x8;
typedef __attribute__((ext_vector_type(4))) float f32x4;

__device__ __forceinline__ float bf2f(u16 h) {
    unsigned int x = ((unsigned int)h) << 16;
    float f;
    __builtin_memcpy(&f, &x, 4);
    return f;
}

__device__ __forceinline__ u16 f2bf(float f) {
    unsigned int x;
    __builtin_memcpy(&x, &f, 4);
    unsigned int r = (x + 0x7FFFu + ((x >> 16) & 1u)) >> 16;  // RNE
    return (u16)r;
}

// ---------------- fp32 -> bf16 convert (vectorized) ----------------
__global__ __launch_bounds__(256) void cvt_f32_bf16(
    const float* __restrict__ in, u16* __restrict__ out, int n4) {
    int i = blockIdx.x * 256 + threadIdx.x;
    int stride = gridDim.x * 256;
    for (; i < n4; i += stride) {
        float4 f = ((const float4*)in)[i];
        ushort4 o;
        o.x = f2bf(f.x); o.y = f2bf(f.y); o.z = f2bf(f.z); o.w = f2bf(f.w);
        ((ushort4*)out)[i] = o;
    }
}

// ---------------- NT GEMM: C[m][n] = sum_k A[m][k] * B[n][k] ----------------
// MODE 0: out bf16 natural + bias   (Q, K projections)
// MODE 1: out bf16 transposed per-batch [b][n][s] + bias (V -> Vt)
// MODE 2: out bf16 natural * scale  (scores)
// MODE 3: out fp32 natural          (PV -> output)
template <int MODE>
__global__ __launch_bounds__(256, 2) void gemm_nt(
    const u16* __restrict__ A, const u16* __restrict__ B,
    void* __restrict__ Cv, const float* __restrict__ bias,
    int K, int ldA, int ldB, int ldC, float scale) {
    __shared__ __align__(16) u16 As[128 * 72];
    __shared__ __align__(16) u16 Bs[128 * 72];

    const int t = threadIdx.x;
    const int lane = t & 63;
    const int wave = t >> 6;
    const int wm = (wave >> 1) * 64;
    const int wn = (wave & 1) * 64;
    const int qd = lane >> 4;
    const int lm = lane & 15;

    const size_t rowA0 = (size_t)blockIdx.y * 128;
    const size_t rowB0 = (size_t)blockIdx.x * 128;

    f32x4 acc[4][4];
#pragma unroll
    for (int i = 0; i < 4; ++i)
#pragma unroll
        for (int j = 0; j < 4; ++j) acc[i][j] = (f32x4){0.f, 0.f, 0.f, 0.f};

    const int sr = t >> 3;          // 0..31 staging row (x4 passes)
    const int sc = (t & 7) * 8;     // staging col in elems

    for (int kb = 0; kb < K; kb += 64) {
#pragma unroll
        for (int p = 0; p < 4; ++p) {
            int row = sr + p * 32;
            *(uint4*)(As + row * 72 + sc) =
                *(const uint4*)(A + (rowA0 + row) * (size_t)ldA + kb + sc);
            *(uint4*)(Bs + row * 72 + sc) =
                *(const uint4*)(B + (rowB0 + row) * (size_t)ldB + kb + sc);
        }
        __syncthreads();
#pragma unroll
        for (int k0 = 0; k0 < 64; k0 += 32) {
            bf16x8 a[4], b[4];
#pragma unroll
            for (int i = 0; i < 4; ++i) {
                a[i] = *(const bf16x8*)(As + (wm + i * 16 + lm) * 72 + k0 + qd * 8);
                b[i] = *(const bf16x8*)(Bs + (wn + i * 16 + lm) * 72 + k0 + qd * 8);
            }
#pragma unroll
            for (int i = 0; i < 4; ++i)
#pragma unroll
                for (int j = 0; j < 4; ++j)
                    acc[i][j] = __builtin_amdgcn_mfma_f32_16x16x32_bf16(
                        a[i], b[j], acc[i][j], 0, 0, 0);
        }
        __syncthreads();
    }

    // epilogue
#pragma unroll
    for (int i = 0; i < 4; ++i) {
        const int r0 = (int)rowA0 + wm + i * 16 + qd * 4;
#pragma unroll
        for (int j = 0; j < 4; ++j) {
            const int col = (int)rowB0 + wn + j * 16 + lm;
            if (MODE == 0) {
                u16* C = (u16*)Cv;
                const float bv = bias[col];
#pragma unroll
                for (int r = 0; r < 4; ++r)
                    C[(size_t)(r0 + r) * ldC + col] = f2bf(acc[i][j][r] + bv);
            } else if (MODE == 1) {
                u16* C = (u16*)Cv;
                const float bv = bias[col];
                const int batch = r0 >> 12;
                const int s0 = r0 & 4095;
                ushort4 o;
                o.x = f2bf(acc[i][j][0] + bv);
                o.y = f2bf(acc[i][j][1] + bv);
                o.z = f2bf(acc[i][j][2] + bv);
                o.w = f2bf(acc[i][j][3] + bv);
                *(ushort4*)(C + (size_t)batch * 4194304 + (size_t)col * 4096 + s0) = o;
            } else if (MODE == 2) {
                u16* C = (u16*)Cv;
#pragma unroll
                for (int r = 0; r < 4; ++r)
                    C[(size_t)(r0 + r) * ldC + col] = f2bf(acc[i][j][r] * scale);
            } else {
                float* C = (float*)Cv;
#pragma unroll
                for (int r = 0; r < 4; ++r)
                    C[(size_t)(r0 + r) * ldC + col] = acc[i][j][r];
            }
        }
    }
}

// ---------------- in-place row softmax over 4096 bf16 ----------------
__global__ __launch_bounds__(256) void softmax_inplace(u16* __restrict__ P) {
    u16* p = P + (size_t)blockIdx.x * 4096;
    const int t = threadIdx.x;
    const int lane = t & 63;
    const int wave = t >> 6;
    __shared__ float redmax[4];
    __shared__ float redsum[4];

    uint4 raw0 = *(const uint4*)(p + t * 8);
    uint4 raw1 = *(const uint4*)(p + 2048 + t * 8);
    float v[16];
    {
        const u16* h0 = (const u16*)&raw0;
        const u16* h1 = (const u16*)&raw1;
#pragma unroll
        for (int i = 0; i < 8; ++i) v[i] = bf2f(h0[i]);
#pragma unroll
        for (int i = 0; i < 8; ++i) v[8 + i] = bf2f(h1[i]);
    }
    float m = v[0];
#pragma unroll
    for (int i = 1; i < 16; ++i) m = fmaxf(m, v[i]);
#pragma unroll
    for (int o = 32; o >= 1; o >>= 1) m = fmaxf(m, __shfl_xor(m, o));
    if (lane == 0) redmax[wave] = m;
    __syncthreads();
    m = fmaxf(fmaxf(redmax[0], redmax[1]), fmaxf(redmax[2], redmax[3]));

    float s = 0.f;
#pragma unroll
    for (int i = 0; i < 16; ++i) {
        v[i] = __expf(v[i] - m);
        s += v[i];
    }
#pragma unroll
    for (int o = 32; o >= 1; o >>= 1) s += __shfl_xor(s, o);
    if (lane == 0) redsum[wave] = s;
    __syncthreads();
    s = redsum[0] + redsum[1] + redsum[2] + redsum[3];
    const float inv = 1.0f / s;

    u16 ho[16];
#pragma unroll
    for (int i = 0; i < 16; ++i) ho[i] = f2bf(v[i] * inv);
    *(uint4*)(p + t * 8) = *(const uint4*)&ho[0];
    *(uint4*)(p + 2048 + t * 8) = *(const uint4*)&ho[8];
}

// ---------------- host launcher ----------------
extern "C" void kernel_launch(void* const* d_in, const int* in_sizes, int n_in,
                              void* d_out, int out_size, void* d_ws, size_t ws_size,
                              hipStream_t stream) {
    const float* x  = (const float*)d_in[0];
    const float* Wq = (const float*)d_in[1];
    const float* bq = (const float*)d_in[2];
    const float* Wk = (const float*)d_in[3];
    const float* bk = (const float*)d_in[4];
    const float* Wv = (const float*)d_in[5];
    const float* bv = (const float*)d_in[6];
    float* out = (float*)d_out;

    // workspace layout (bytes): all 128B-aligned by construction
    char* w = (char*)d_ws;
    u16* x_bf  = (u16*)w; w += 33554432;  // 16M elems
    u16* wq_bf = (u16*)w; w += 2097152;   // 1M
    u16* wk_bf = (u16*)w; w += 2097152;
    u16* wv_bf = (u16*)w; w += 2097152;
    u16* Qb    = (u16*)w; w += 33554432;  // [B*S][D] bf16
    u16* Kb    = (u16*)w; w += 33554432;
    u16* Vt    = (u16*)w; w += 33554432;  // [B][D][S] bf16
    u16* SP    = (u16*)w; w += 33554432;  // [S][S] bf16, reused per batch

    // 1) convert inputs to bf16
    cvt_f32_bf16<<<2048, 256, 0, stream>>>(x, x_bf, 4194304);
    cvt_f32_bf16<<<512, 256, 0, stream>>>(Wq, wq_bf, 262144);
    cvt_f32_bf16<<<512, 256, 0, stream>>>(Wk, wk_bf, 262144);
    cvt_f32_bf16<<<512, 256, 0, stream>>>(Wv, wv_bf, 262144);

    // 2) projections: M=16384, N=1024, K=1024
    dim3 gp(8, 128, 1);
    gemm_nt<0><<<gp, 256, 0, stream>>>(x_bf, wq_bf, Qb, bq, 1024, 1024, 1024, 1024, 1.f);
    gemm_nt<0><<<gp, 256, 0, stream>>>(x_bf, wk_bf, Kb, bk, 1024, 1024, 1024, 1024, 1.f);
    gemm_nt<1><<<gp, 256, 0, stream>>>(x_bf, wv_bf, Vt, bv, 1024, 1024, 1024, 4096, 1.f);

    // 3) per batch: scores -> softmax -> PV
    for (int b = 0; b < 4; ++b) {
        const size_t off = (size_t)b * 4194304;  // S*D elems (also S*D out stride)
        gemm_nt<2><<<dim3(32, 32, 1), 256, 0, stream>>>(
            Qb + off, Kb + off, SP, nullptr, 1024, 1024, 1024, 4096, 0.03125f);
        softmax_inplace<<<4096, 256, 0, stream>>>(SP);
        gemm_nt<3><<<dim3(8, 32, 1), 256, 0, stream>>>(
            SP, Vt + off, out + off, nullptr, 4096, 4096, 4096, 1024, 1.f);
    }
}

// Round 2
// 606.956 us; speedup vs baseline: 1.3695x; 1.3695x over previous
//
#include <hip/hip_runtime.h>

// Self-attention B=4, S=4096, D=1024, fp32 in/out.
// Round 2: (1) global_load_lds width=16 staging with XOR chunk swizzle
// (conflict-benign ds_read_b128), (2) z-batched dispatches: fused QKV proj,
// batched scores / softmax / PV when ws_size allows 4 score buffers.

typedef unsigned short u16;
typedef __attribute__((ext_vector_type(8))) short bf16x8;
typedef __attribute__((ext_vector_type(4))) float f32x4;

__device__ __forceinline__ float bf2f(u16 h) {
    unsigned int x = ((unsigned int)h) << 16;
    float f;
    __builtin_memcpy(&f, &x, 4);
    return f;
}

__device__ __forceinline__ u16 f2bf(float f) {
    unsigned int x;
    __builtin_memcpy(&x, &f, 4);
    unsigned int r = (x + 0x7FFFu + ((x >> 16) & 1u)) >> 16;  // RNE
    return (u16)r;
}

__device__ __forceinline__ void load16_lds(const u16* g, u16* l) {
    __builtin_amdgcn_global_load_lds(
        (const __attribute__((address_space(1))) void*)g,
        (__attribute__((address_space(3))) void*)l, 16, 0, 0);
}

// ---------------- fp32 -> bf16 convert (vectorized) ----------------
__global__ __launch_bounds__(256) void cvt_f32_bf16(
    const float* __restrict__ in, u16* __restrict__ out, int n4) {
    int i = blockIdx.x * 256 + threadIdx.x;
    int stride = gridDim.x * 256;
    for (; i < n4; i += stride) {
        float4 f = ((const float4*)in)[i];
        ushort4 o;
        o.x = f2bf(f.x); o.y = f2bf(f.y); o.z = f2bf(f.z); o.w = f2bf(f.w);
        ((ushort4*)out)[i] = o;
    }
}

// ---------------- shared MFMA core: 128x128 tile, BK=64, 4 waves 2x2 ----
// LDS layout: unpadded 64-elem rows (128 B), source chunks XOR-swizzled by
// (row&7) so ds_read_b128 fragment reads alias <=2-way per bank group.
// C/D layout (m89): col = lane&15, row = (lane>>4)*4 + reg.
__device__ __forceinline__ void mfma_core(
    const u16* __restrict__ A, const u16* __restrict__ B, int K, int ldA,
    int ldB, size_t rowA0, size_t rowB0, u16* As, u16* Bs, f32x4 acc[4][4]) {
    const int t = threadIdx.x;
    const int lane = t & 63;
    const int wave = t >> 6;
    const int wm = (wave >> 1) * 64;
    const int wn = (wave & 1) * 64;
    const int lm = lane & 15;
    const int qd = lane >> 4;
    const int kx = lm & 7;
    const int rl = lane >> 3;                 // row within an 8-row call
    const int swz = ((lane & 7) ^ rl) << 3;   // swizzled source chunk (elems)

#pragma unroll
    for (int i = 0; i < 4; ++i)
#pragma unroll
        for (int j = 0; j < 4; ++j) acc[i][j] = (f32x4){0.f, 0.f, 0.f, 0.f};

    // each wave stages 4 calls x 8 rows for A and B (rows wave*32..wave*32+31)
    const u16* ga = A + (rowA0 + (size_t)(wave * 32 + rl)) * (size_t)ldA + swz;
    const u16* gb = B + (rowB0 + (size_t)(wave * 32 + rl)) * (size_t)ldB + swz;
    u16* la = As + wave * 2048;  // 4 calls * 512 elems
    u16* lb = Bs + wave * 2048;

    for (int kb = 0; kb < K; kb += 64) {
#pragma unroll
        for (int p = 0; p < 4; ++p) {
            load16_lds(ga + (size_t)(p * 8) * ldA + kb, la + p * 512);
            load16_lds(gb + (size_t)(p * 8) * ldB + kb, lb + p * 512);
        }
        __syncthreads();
#pragma unroll
        for (int k0 = 0; k0 < 64; k0 += 32) {
            const int q0 = k0 >> 3;  // chunk base: 0 or 4
            const int cofs = (((q0 + qd) ^ kx) << 3);
            bf16x8 a[4], b[4];
#pragma unroll
            for (int i = 0; i < 4; ++i) {
                a[i] = *(const bf16x8*)(As + (wm + i * 16 + lm) * 64 + cofs);
                b[i] = *(const bf16x8*)(Bs + (wn + i * 16 + lm) * 64 + cofs);
            }
#pragma unroll
            for (int i = 0; i < 4; ++i)
#pragma unroll
                for (int j = 0; j < 4; ++j)
                    acc[i][j] = __builtin_amdgcn_mfma_f32_16x16x32_bf16(
                        a[i], b[j], acc[i][j], 0, 0, 0);
        }
        __syncthreads();
    }
}

// ---------------- fused QKV projection ----------------
// z=0: Qb natural, z=1: Kb natural, z=2: Vt transposed [b][d][s]; all + bias.
__global__ __launch_bounds__(256, 3) void proj_qkv(
    const u16* __restrict__ x, const u16* __restrict__ w0,
    const u16* __restrict__ w1, const u16* __restrict__ w2,
    const float* __restrict__ b0, const float* __restrict__ b1,
    const float* __restrict__ b2, u16* __restrict__ Qb, u16* __restrict__ Kb,
    u16* __restrict__ Vt) {
    __shared__ __align__(16) u16 As[128 * 64];
    __shared__ __align__(16) u16 Bs[128 * 64];
    const int z = blockIdx.z;
    const u16* W = (z == 0) ? w0 : (z == 1) ? w1 : w2;
    const float* bias = (z == 0) ? b0 : (z == 1) ? b1 : b2;

    const size_t rowA0 = (size_t)blockIdx.y * 128;
    const size_t rowB0 = (size_t)blockIdx.x * 128;
    f32x4 acc[4][4];
    mfma_core(x, W, 1024, 1024, 1024, rowA0, rowB0, As, Bs, acc);

    const int lane = threadIdx.x & 63;
    const int wave = threadIdx.x >> 6;
    const int wm = (wave >> 1) * 64;
    const int wn = (wave & 1) * 64;
    const int lm = lane & 15;
    const int qd = lane >> 4;

#pragma unroll
    for (int i = 0; i < 4; ++i) {
        const int r0 = (int)rowA0 + wm + i * 16 + qd * 4;
#pragma unroll
        for (int j = 0; j < 4; ++j) {
            const int col = (int)rowB0 + wn + j * 16 + lm;
            const float bv = bias[col];
            if (z < 2) {
                u16* C = z ? Kb : Qb;
#pragma unroll
                for (int r = 0; r < 4; ++r)
                    C[(size_t)(r0 + r) * 1024 + col] = f2bf(acc[i][j][r] + bv);
            } else {
                const int batch = r0 >> 12;
                const int s0 = r0 & 4095;
                ushort4 o;
                o.x = f2bf(acc[i][j][0] + bv);
                o.y = f2bf(acc[i][j][1] + bv);
                o.z = f2bf(acc[i][j][2] + bv);
                o.w = f2bf(acc[i][j][3] + bv);
                *(ushort4*)(Vt + (size_t)batch * 4194304 + (size_t)col * 4096 + s0) = o;
            }
        }
    }
}

// ---------------- generic NT GEMM, z-strided ----------------
// MODE 2: out bf16 * scale (scores);  MODE 3: out fp32 (PV).
template <int MODE>
__global__ __launch_bounds__(256, 3) void gemm_nt(
    const u16* __restrict__ A0, const u16* __restrict__ B0,
    void* __restrict__ Cv, int K, int ldA, int ldB, int ldC, float scale,
    size_t sAz, size_t sBz, size_t sCz) {
    __shared__ __align__(16) u16 As[128 * 64];
    __shared__ __align__(16) u16 Bs[128 * 64];
    const size_t z = blockIdx.z;
    const u16* A = A0 + z * sAz;
    const u16* B = B0 + z * sBz;

    const size_t rowA0 = (size_t)blockIdx.y * 128;
    const size_t rowB0 = (size_t)blockIdx.x * 128;
    f32x4 acc[4][4];
    mfma_core(A, B, K, ldA, ldB, rowA0, rowB0, As, Bs, acc);

    const int lane = threadIdx.x & 63;
    const int wave = threadIdx.x >> 6;
    const int wm = (wave >> 1) * 64;
    const int wn = (wave & 1) * 64;
    const int lm = lane & 15;
    const int qd = lane >> 4;

#pragma unroll
    for (int i = 0; i < 4; ++i) {
        const int r0 = (int)rowA0 + wm + i * 16 + qd * 4;
#pragma unroll
        for (int j = 0; j < 4; ++j) {
            const int col = (int)rowB0 + wn + j * 16 + lm;
            if (MODE == 2) {
                u16* C = (u16*)Cv + z * sCz;
#pragma unroll
                for (int r = 0; r < 4; ++r)
                    C[(size_t)(r0 + r) * ldC + col] = f2bf(acc[i][j][r] * scale);
            } else {
                float* C = (float*)Cv + z * sCz;
#pragma unroll
                for (int r = 0; r < 4; ++r)
                    C[(size_t)(r0 + r) * ldC + col] = acc[i][j][r];
            }
        }
    }
}

// ---------------- in-place row softmax over 4096 bf16 ----------------
__global__ __launch_bounds__(256) void softmax_inplace(u16* __restrict__ P) {
    u16* p = P + (size_t)blockIdx.x * 4096;
    const int t = threadIdx.x;
    const int lane = t & 63;
    const int wave = t >> 6;
    __shared__ float redmax[4];
    __shared__ float redsum[4];

    uint4 raw0 = *(const uint4*)(p + t * 8);
    uint4 raw1 = *(const uint4*)(p + 2048 + t * 8);
    float v[16];
    {
        const u16* h0 = (const u16*)&raw0;
        const u16* h1 = (const u16*)&raw1;
#pragma unroll
        for (int i = 0; i < 8; ++i) v[i] = bf2f(h0[i]);
#pragma unroll
        for (int i = 0; i < 8; ++i) v[8 + i] = bf2f(h1[i]);
    }
    float m = v[0];
#pragma unroll
    for (int i = 1; i < 16; ++i) m = fmaxf(m, v[i]);
#pragma unroll
    for (int o = 32; o >= 1; o >>= 1) m = fmaxf(m, __shfl_xor(m, o));
    if (lane == 0) redmax[wave] = m;
    __syncthreads();
    m = fmaxf(fmaxf(redmax[0], redmax[1]), fmaxf(redmax[2], redmax[3]));

    float s = 0.f;
#pragma unroll
    for (int i = 0; i < 16; ++i) {
        v[i] = __expf(v[i] - m);
        s += v[i];
    }
#pragma unroll
    for (int o = 32; o >= 1; o >>= 1) s += __shfl_xor(s, o);
    if (lane == 0) redsum[wave] = s;
    __syncthreads();
    s = redsum[0] + redsum[1] + redsum[2] + redsum[3];
    const float inv = 1.0f / s;

    u16 ho[16];
#pragma unroll
    for (int i = 0; i < 16; ++i) ho[i] = f2bf(v[i] * inv);
    *(uint4*)(p + t * 8) = *(const uint4*)&ho[0];
    *(uint4*)(p + 2048 + t * 8) = *(const uint4*)&ho[8];
}

// ---------------- host launcher ----------------
extern "C" void kernel_launch(void* const* d_in, const int* in_sizes, int n_in,
                              void* d_out, int out_size, void* d_ws, size_t ws_size,
                              hipStream_t stream) {
    const float* x  = (const float*)d_in[0];
    const float* Wq = (const float*)d_in[1];
    const float* bq = (const float*)d_in[2];
    const float* Wk = (const float*)d_in[3];
    const float* bk = (const float*)d_in[4];
    const float* Wv = (const float*)d_in[5];
    const float* bv = (const float*)d_in[6];
    float* out = (float*)d_out;

    const bool big = ws_size >= (size_t)224 * 1024 * 1024;
    char* w = (char*)d_ws;
    u16 *x_bf, *wq_bf, *wk_bf, *wv_bf, *Qb, *Kb, *Vt, *SP;
    if (big) {
        // SP[4] occupies [0,128MiB); x_bf + W bufs alias its head (dead
        // before SP is written — stream order guarantees proj finished).
        SP    = (u16*)(w);
        x_bf  = (u16*)(w);
        wq_bf = (u16*)(w + 33554432);
        wk_bf = (u16*)(w + 35651584);
        wv_bf = (u16*)(w + 37748736);
        Qb    = (u16*)(w + 134217728);
        Kb    = (u16*)(w + 167772160);
        Vt    = (u16*)(w + 201326592);
    } else {
        x_bf  = (u16*)(w);
        wq_bf = (u16*)(w + 33554432);
        wk_bf = (u16*)(w + 35651584);
        wv_bf = (u16*)(w + 37748736);
        Qb    = (u16*)(w + 39845888);
        Kb    = (u16*)(w + 73400320);
        Vt    = (u16*)(w + 106954752);
        SP    = (u16*)(w + 140509184);  // single 32 MiB buffer
    }

    // 1) convert inputs to bf16
    cvt_f32_bf16<<<2048, 256, 0, stream>>>(x, x_bf, 4194304);
    cvt_f32_bf16<<<512, 256, 0, stream>>>(Wq, wq_bf, 262144);
    cvt_f32_bf16<<<512, 256, 0, stream>>>(Wk, wk_bf, 262144);
    cvt_f32_bf16<<<512, 256, 0, stream>>>(Wv, wv_bf, 262144);

    // 2) fused projections: M=16384, N=1024, K=1024, z = {Q,K,V}
    proj_qkv<<<dim3(8, 128, 3), 256, 0, stream>>>(
        x_bf, wq_bf, wk_bf, wv_bf, bq, bk, bv, Qb, Kb, Vt);

    if (big) {
        // 3) batched scores: [b] Q Kt /32 -> bf16
        gemm_nt<2><<<dim3(32, 32, 4), 256, 0, stream>>>(
            Qb, Kb, SP, 1024, 1024, 1024, 4096, 0.03125f,
            4194304, 4194304, 16777216);
        // 4) batched softmax over all 16384 rows
        softmax_inplace<<<16384, 256, 0, stream>>>(SP);
        // 5) batched PV: O = P Vt -> fp32
        gemm_nt<3><<<dim3(8, 32, 4), 256, 0, stream>>>(
            SP, Vt, out, 4096, 4096, 4096, 1024, 1.f,
            16777216, 4194304, 4194304);
    } else {
        for (int b = 0; b < 4; ++b) {
            const size_t off = (size_t)b * 4194304;
            gemm_nt<2><<<dim3(32, 32, 1), 256, 0, stream>>>(
                Qb + off, Kb + off, SP, 1024, 1024, 1024, 4096, 0.03125f,
                0, 0, 0);
            softmax_inplace<<<4096, 256, 0, stream>>>(SP);
            gemm_nt<3><<<dim3(8, 32, 1), 256, 0, stream>>>(
                SP, Vt + off, out + off, 4096, 4096, 4096, 1024, 1.f,
                0, 0, 0);
        }
    }
}